// Round 18
// baseline (218.647 us; speedup 1.0000x reference)
//
#include <hip/hip_runtime.h>
#include <math.h>

// GCN forward: coarse-bucket counting-sort CSR + node-parallel bf16 gather.
// Measured models (R4-R17):
//   - device-scope atomic ~= 35B fabric + ~41ns -> minimize atomic COUNT.
//   - k_bin WRITE scales with fragments = blocks x buckets (R11/R16); bin is
//     at its floor ~40us (R17: 512thr null; 2x26MB reads + 13MB writes + LDS
//     atomics). Do not touch.
//   - gathers instruction-bound, not byte-bound (R9 vs R12): wide lanes win
//     (R15: 8-lane uint2 -43us). Broadcast esrc loads (R13: shfl-distribution
//     serializes). THIS ROUND: gather_score 4-lane uint4 (halve instrs again).
//   - gemm1 R17: occ 12.6%, 42us -> wave-scarce latency-bound. THIS ROUND:
//     split-K 2-way (2 lanes/row, shfl_xor combine) doubles waves.
//   - hipMemsetAsync(1KB) showed as 42.8us fillBuffer dispatch -> replaced
//     with 1-block k_zero (tests queue-pathology hypothesis).
// Pipeline: k_zero -> k_bin(512thr) -> k_bukscan -> k_place(1024thr) ->
//   k_gemm1(splitK) -> k_gather_fuse(8-lane) ->
//   k_gather_score(4-lane, +softmax partial) -> k_sm_fin -> k_sm_out.

static inline int cdiv(long a, int b) { return (int)((a + (long)b - 1) / b); }

#define EPB 8192      // edges per k_bin block (391 blocks @ E=3.2M)
#define NBMAX 256     // max buckets (N <= 131072 @ 512 nodes/bucket)
#define CAP 17408     // per-bucket capacity; mean 16384, +8 sigma

typedef unsigned short u16;
typedef int iv4 __attribute__((ext_vector_type(4)));

__device__ __forceinline__ u16 f2bf(float f) {  // RNE f32->bf16
  unsigned u = __float_as_uint(f);
  return (u16)((u + 0x7FFFu + ((u >> 16) & 1u)) >> 16);
}
__device__ __forceinline__ float lo16f(unsigned v) {
  return __uint_as_float(v << 16);
}
__device__ __forceinline__ float hi16f(unsigned v) {
  return __uint_as_float(v & 0xFFFF0000u);
}

__global__ void k_zero(unsigned* __restrict__ p, int n) {
  int i = threadIdx.x;
  if (i < n) p[i] = 0u;
}

// --- binning: LDS hist -> one reservation atomic per (block,bucket) -> fill runs
__global__ __launch_bounds__(512) void k_bin(const int* __restrict__ src,
                                             const int* __restrict__ dst,
                                             unsigned* __restrict__ gcur,
                                             unsigned* __restrict__ ebuf,
                                             int E, int nbuk) {
  __shared__ unsigned lhist[NBMAX];
  __shared__ unsigned lcur[NBMAX];
  int tid = threadIdx.x;
  for (int i = tid; i < nbuk; i += 512) lhist[i] = 0;
  __syncthreads();
  int e0 = blockIdx.x * EPB, e1 = min(e0 + EPB, E);
  int nvec = (e1 - e0) >> 11;  // 2048-edge chunks (512 thr x 4)
  for (int k = 0; k < nvec; ++k) {
    iv4 d4 = __builtin_nontemporal_load((const iv4*)(dst + e0 + (k << 11) + tid * 4));
    atomicAdd(&lhist[d4.x >> 9], 1u);
    atomicAdd(&lhist[d4.y >> 9], 1u);
    atomicAdd(&lhist[d4.z >> 9], 1u);
    atomicAdd(&lhist[d4.w >> 9], 1u);
  }
  for (int e = e0 + (nvec << 11) + tid; e < e1; e += 512)
    atomicAdd(&lhist[__builtin_nontemporal_load(&dst[e]) >> 9], 1u);
  __syncthreads();
  for (int b = tid; b < nbuk; b += 512) {
    unsigned nn = lhist[b];
    lcur[b] = nn ? atomicAdd(&gcur[b], nn) : 0u;  // run reservation
  }
  __syncthreads();
  for (int k = 0; k < nvec; ++k) {
    int base = e0 + (k << 11) + tid * 4;
    iv4 d4 = __builtin_nontemporal_load((const iv4*)(dst + base));
    iv4 s4 = __builtin_nontemporal_load((const iv4*)(src + base));
#define PUT(dd, ss)                                              \
    {                                                            \
      int bb = (dd) >> 9;                                        \
      unsigned off = atomicAdd(&lcur[bb], 1u);                   \
      if (off < CAP)                                             \
        ebuf[(size_t)bb * CAP + off] =                           \
            ((unsigned)((dd) & 511) << 17) | (unsigned)(ss);     \
    }
    PUT(d4.x, s4.x) PUT(d4.y, s4.y) PUT(d4.z, s4.z) PUT(d4.w, s4.w)
  }
  for (int e = e0 + (nvec << 11) + tid; e < e1; e += 512) {
    int d = __builtin_nontemporal_load(&dst[e]);
    int s = __builtin_nontemporal_load(&src[e]);
    PUT(d, s)
  }
#undef PUT
}

// --- exclusive scan of bucket counts (one block; nbuk <= 256)
__global__ __launch_bounds__(256) void k_bukscan(const unsigned* __restrict__ gcur,
                                                 unsigned* __restrict__ bbase,
                                                 int* __restrict__ rowptr,
                                                 int nbuk, int N) {
  __shared__ unsigned sm[256];
  int t = threadIdx.x;
  unsigned v = (t < nbuk) ? min(gcur[t], (unsigned)CAP) : 0u;
  sm[t] = v;
  __syncthreads();
  for (int o = 1; o < 256; o <<= 1) {
    unsigned add = (t >= o) ? sm[t - o] : 0u;
    __syncthreads();
    sm[t] += add;
    __syncthreads();
  }
  if (t < nbuk) bbase[t] = sm[t] - v;  // exclusive
  if (t == 255) rowptr[N] = (int)sm[255];
}

// --- per-bucket (512 nodes, 1024 threads): LDS count+scan -> rowptr/dinv;
// sort run into esrc.
__global__ __launch_bounds__(1024) void k_place(const unsigned* __restrict__ gcur,
                                                const unsigned* __restrict__ ebuf,
                                                const unsigned* __restrict__ bbase,
                                                int* __restrict__ rowptr,
                                                float* __restrict__ dinv,
                                                int* __restrict__ esrc, int N) {
  __shared__ unsigned lcnt[512];
  __shared__ unsigned lofs[512];
  int b = blockIdx.x, tid = threadIdx.x;
  if (tid < 512) lcnt[tid] = 0;
  __syncthreads();
  int cnt = min((int)gcur[b], CAP);
  const unsigned* eb = ebuf + (size_t)b * CAP;
  for (int j = tid; j < cnt; j += 1024) atomicAdd(&lcnt[eb[j] >> 17], 1u);
  __syncthreads();
  unsigned myc = (tid < 512) ? lcnt[tid] : 0u;
  if (tid < 512) lofs[tid] = myc;
  __syncthreads();
  for (int o = 1; o < 512; o <<= 1) {  // inclusive scan over 512
    unsigned add = (tid < 512 && tid >= o) ? lofs[tid - o] : 0u;
    __syncthreads();
    if (tid < 512) lofs[tid] += add;
    __syncthreads();
  }
  unsigned base = bbase[b];
  if (tid < 512) {
    unsigned ex = lofs[tid] - myc;  // exclusive
    int node = (b << 9) + tid;
    if (node < N) {
      rowptr[node] = (int)(base + ex);
      dinv[node] = rsqrtf((float)myc + 1.0f);  // deg = cnt + self-loop
    }
    lofs[tid] = ex;  // reuse as cursor
  }
  __syncthreads();
  for (int j = tid; j < cnt; j += 1024) {
    unsigned p = eb[j];
    unsigned r = atomicAdd(&lofs[p >> 17], 1u);  // LDS atomic
    esrc[base + r] = (int)(p & 0x1FFFF);
  }
}

// hWs = bf16(dinv[r] * (x @ W1)); TWO LANES PER ROW (split-K), shfl combine.
// Lane h of pair handles features [h*64, h*64+64); 2x waves vs row-per-thread.
__global__ __launch_bounds__(256) void k_gemm1(
    const float* __restrict__ x, const float* __restrict__ W1,
    const float* __restrict__ dinv, u16* __restrict__ hWs, int N) {
  __shared__ float4 w[128 * 8];  // w[k][q] = W1[k][4q..4q+3]
  for (int i = threadIdx.x; i < 1024; i += 256) w[i] = ((const float4*)W1)[i];
  __syncthreads();
  int gid = blockIdx.x * 256 + threadIdx.x;
  int r = gid >> 1, h = gid & 1;
  if (r >= N) return;
  const float4* xr = (const float4*)(x + (size_t)r * 128) + h * 16;
  float acc[32];
#pragma unroll
  for (int c = 0; c < 32; ++c) acc[c] = 0.f;
  for (int k4 = 0; k4 < 16; ++k4) {
    float4 xv = xr[k4];
    int kb = (h * 16 + k4) * 4;
#pragma unroll
    for (int kk = 0; kk < 4; ++kk) {
      float xk = (kk == 0) ? xv.x : (kk == 1) ? xv.y : (kk == 2) ? xv.z : xv.w;
      const float4* wk = &w[(kb + kk) * 8];
#pragma unroll
      for (int q = 0; q < 8; ++q) {
        float4 wv = wk[q];
        acc[q * 4 + 0] = fmaf(xk, wv.x, acc[q * 4 + 0]);
        acc[q * 4 + 1] = fmaf(xk, wv.y, acc[q * 4 + 1]);
        acc[q * 4 + 2] = fmaf(xk, wv.z, acc[q * 4 + 2]);
        acc[q * 4 + 3] = fmaf(xk, wv.w, acc[q * 4 + 3]);
      }
    }
  }
  // combine the two K-halves (lanes 2i, 2i+1 hold the same row)
#pragma unroll
  for (int c = 0; c < 32; ++c) acc[c] += __shfl_xor(acc[c], 1, 64);
  float dv = dinv[r];
  // lane h packs+stores columns [h*16, h*16+16)
  unsigned pk[8];
#pragma unroll
  for (int q = 0; q < 8; ++q) {
    int c0 = h * 16 + 2 * q;
    pk[q] = (unsigned)f2bf(dv * acc[c0]) | ((unsigned)f2bf(dv * acc[c0 + 1]) << 16);
  }
  uint4* o4 = (uint4*)(hWs + (size_t)r * 32) + h * 2;
  o4[0] = make_uint4(pk[0], pk[1], pk[2], pk[3]);
  o4[1] = make_uint4(pk[4], pk[5], pk[6], pk[7]);
}

// accumulate 4 bf16 columns from packed uint2
#define ACC4(A, U)                \
  {                               \
    A.x += lo16f((U).x);          \
    A.y += hi16f((U).x);          \
    A.z += lo16f((U).y);          \
    A.w += hi16f((U).y);          \
  }

// layer-1 gather fused with layer-2 transform. 8 lanes/node, lane = 4 columns.
__global__ __launch_bounds__(256) void k_gather_fuse(
    const int* __restrict__ esrc, const int* __restrict__ rowptr,
    const float* __restrict__ dinv, const uint2* __restrict__ hWs1,
    const float* __restrict__ b1, const float* __restrict__ W2,
    uint2* __restrict__ hWs2, int N) {
  __shared__ float4 w2[32 * 8];  // w2[k][q] = W2[k][4q..4q+3]
  w2[threadIdx.x] = ((const float4*)W2)[threadIdx.x];
  __syncthreads();
  int gid = blockIdx.x * 256 + threadIdx.x;
  int i = gid >> 3, c = gid & 7;
  if (i >= N) return;
  uint2 v = hWs1[(size_t)i * 8 + c];
  float4 acc = make_float4(lo16f(v.x), hi16f(v.x), lo16f(v.y), hi16f(v.y));
  int beg = rowptr[i], end = rowptr[i + 1];
  int j = beg;
  for (; j + 7 < end; j += 8) {
    int s0 = esrc[j + 0], s1 = esrc[j + 1], s2 = esrc[j + 2], s3 = esrc[j + 3];
    int s4 = esrc[j + 4], s5 = esrc[j + 5], s6 = esrc[j + 6], s7 = esrc[j + 7];
    uint2 u0 = hWs1[(size_t)s0 * 8 + c];
    uint2 u1 = hWs1[(size_t)s1 * 8 + c];
    uint2 u2 = hWs1[(size_t)s2 * 8 + c];
    uint2 u3 = hWs1[(size_t)s3 * 8 + c];
    uint2 u4 = hWs1[(size_t)s4 * 8 + c];
    uint2 u5 = hWs1[(size_t)s5 * 8 + c];
    uint2 u6 = hWs1[(size_t)s6 * 8 + c];
    uint2 u7 = hWs1[(size_t)s7 * 8 + c];
    ACC4(acc, u0) ACC4(acc, u1) ACC4(acc, u2) ACC4(acc, u3)
    ACC4(acc, u4) ACC4(acc, u5) ACC4(acc, u6) ACC4(acc, u7)
  }
  for (; j < end; ++j) {
    uint2 u = hWs1[(size_t)esrc[j] * 8 + c];
    ACC4(acc, u)
  }
  float dv = dinv[i];
  float4 bv = ((const float4*)b1)[c];
  float4 r4;
  r4.x = fmaxf(fmaf(dv, acc.x, bv.x), 0.f);
  r4.y = fmaxf(fmaf(dv, acc.y, bv.y), 0.f);
  r4.z = fmaxf(fmaf(dv, acc.z, bv.z), 0.f);
  r4.w = fmaxf(fmaf(dv, acc.w, bv.w), 0.f);
  float4 a2 = make_float4(0.f, 0.f, 0.f, 0.f);
#pragma unroll
  for (int k8 = 0; k8 < 8; ++k8) {
    float4 rr;
    rr.x = __shfl(r4.x, k8, 8);
    rr.y = __shfl(r4.y, k8, 8);
    rr.z = __shfl(r4.z, k8, 8);
    rr.w = __shfl(r4.w, k8, 8);
    float4 wv;
    wv = w2[(4 * k8 + 0) * 8 + c];
    a2.x = fmaf(rr.x, wv.x, a2.x); a2.y = fmaf(rr.x, wv.y, a2.y);
    a2.z = fmaf(rr.x, wv.z, a2.z); a2.w = fmaf(rr.x, wv.w, a2.w);
    wv = w2[(4 * k8 + 1) * 8 + c];
    a2.x = fmaf(rr.y, wv.x, a2.x); a2.y = fmaf(rr.y, wv.y, a2.y);
    a2.z = fmaf(rr.y, wv.z, a2.z); a2.w = fmaf(rr.y, wv.w, a2.w);
    wv = w2[(4 * k8 + 2) * 8 + c];
    a2.x = fmaf(rr.z, wv.x, a2.x); a2.y = fmaf(rr.z, wv.y, a2.y);
    a2.z = fmaf(rr.z, wv.z, a2.z); a2.w = fmaf(rr.z, wv.w, a2.w);
    wv = w2[(4 * k8 + 3) * 8 + c];
    a2.x = fmaf(rr.w, wv.x, a2.x); a2.y = fmaf(rr.w, wv.y, a2.y);
    a2.z = fmaf(rr.w, wv.z, a2.z); a2.w = fmaf(rr.w, wv.w, a2.w);
  }
  uint2 o;
  o.x = (unsigned)f2bf(dv * a2.x) | ((unsigned)f2bf(dv * a2.y) << 16);
  o.y = (unsigned)f2bf(dv * a2.z) | ((unsigned)f2bf(dv * a2.w) << 16);
  hWs2[(size_t)i * 8 + c] = o;
}

// accumulate 8 bf16 columns from packed uint4
#define ACC8(A, U)                                        \
  {                                                       \
    A[0] += lo16f((U).x); A[1] += hi16f((U).x);           \
    A[2] += lo16f((U).y); A[3] += hi16f((U).y);           \
    A[4] += lo16f((U).z); A[5] += hi16f((U).z);           \
    A[6] += lo16f((U).w); A[7] += hi16f((U).w);           \
  }

// layer-2 gather + score head + per-block softmax partial.
// 4 lanes/node, lane = 8 columns (uint4). 64 nodes per 256-thread block.
__global__ __launch_bounds__(256) void k_gather_score(
    const int* __restrict__ esrc, const int* __restrict__ rowptr,
    const float* __restrict__ dinv, const uint4* __restrict__ hWs,
    const float* __restrict__ bias, const float* __restrict__ Wh,
    const float* __restrict__ bh, const float* __restrict__ cash,
    float* __restrict__ scores, float2* __restrict__ part, int N) {
  __shared__ float sc[64];
  int gid = blockIdx.x * 256 + threadIdx.x;
  if (gid == 0) scores[0] = cash[0];
  if (threadIdx.x < 64) sc[threadIdx.x] = -3.4e38f;
  __syncthreads();
  int i = gid >> 2, c = gid & 3;
  if (i < N) {
    uint4 v = hWs[(size_t)i * 4 + c];
    float a[8];
    a[0] = lo16f(v.x); a[1] = hi16f(v.x);
    a[2] = lo16f(v.y); a[3] = hi16f(v.y);
    a[4] = lo16f(v.z); a[5] = hi16f(v.z);
    a[6] = lo16f(v.w); a[7] = hi16f(v.w);
    int beg = rowptr[i], end = rowptr[i + 1];
    int j = beg;
    for (; j + 3 < end; j += 4) {
      int s0 = esrc[j + 0], s1 = esrc[j + 1], s2 = esrc[j + 2], s3 = esrc[j + 3];
      uint4 u0 = hWs[(size_t)s0 * 4 + c];
      uint4 u1 = hWs[(size_t)s1 * 4 + c];
      uint4 u2 = hWs[(size_t)s2 * 4 + c];
      uint4 u3 = hWs[(size_t)s3 * 4 + c];
      ACC8(a, u0) ACC8(a, u1) ACC8(a, u2) ACC8(a, u3)
    }
    for (; j < end; ++j) {
      uint4 u = hWs[(size_t)esrc[j] * 4 + c];
      ACC8(a, u)
    }
    float dv = dinv[i];
    const float4* bv4 = (const float4*)bias;
    const float4* wh4 = (const float4*)Wh;
    float4 b0 = bv4[c * 2], b1v = bv4[c * 2 + 1];
    float4 w0 = wh4[c * 2], w1v = wh4[c * 2 + 1];
    float t = fmaxf(fmaf(dv, a[0], b0.x), 0.f) * w0.x +
              fmaxf(fmaf(dv, a[1], b0.y), 0.f) * w0.y +
              fmaxf(fmaf(dv, a[2], b0.z), 0.f) * w0.z +
              fmaxf(fmaf(dv, a[3], b0.w), 0.f) * w0.w +
              fmaxf(fmaf(dv, a[4], b1v.x), 0.f) * w1v.x +
              fmaxf(fmaf(dv, a[5], b1v.y), 0.f) * w1v.y +
              fmaxf(fmaf(dv, a[6], b1v.z), 0.f) * w1v.z +
              fmaxf(fmaf(dv, a[7], b1v.w), 0.f) * w1v.w;
    t += __shfl_xor(t, 1, 4);
    t += __shfl_xor(t, 2, 4);
    if (c == 0) {
      float s = t + bh[0];
      scores[1 + i] = s;
      sc[threadIdx.x >> 2] = s;
    }
  }
  __syncthreads();
  if (threadIdx.x < 64) {  // exact (max,sumexp) over this block's 64 scores
    float vv = sc[threadIdx.x];
    float m = vv;
#pragma unroll
    for (int o = 32; o >= 1; o >>= 1) m = fmaxf(m, __shfl_xor(m, o, 64));
    float e = (vv > -3.0e38f) ? expf(vv - m) : 0.f;
#pragma unroll
    for (int o = 32; o >= 1; o >>= 1) e += __shfl_xor(e, o, 64);
    if (threadIdx.x == 0) part[blockIdx.x] = make_float2(m, e);
  }
}

// --- final softmax reduce: merge block partials + cash (thread 0) ---
__global__ __launch_bounds__(256) void k_sm_fin(const float2* __restrict__ part,
                                                int nparts,
                                                const float* __restrict__ scores,
                                                float* __restrict__ finals) {
  float m = (threadIdx.x == 0) ? scores[0] : -3.4e38f;  // cash
  float s = (threadIdx.x == 0) ? 1.f : 0.f;
  for (int i = threadIdx.x; i < nparts; i += 256) {
    float2 p = part[i];
    if (p.x > m) { s = s * expf(m - p.x) + p.y; m = p.x; }
    else s += p.y * expf(p.x - m);
  }
  __shared__ float sm_m[256], sm_s[256];
  sm_m[threadIdx.x] = m; sm_s[threadIdx.x] = s;
  __syncthreads();
  for (int o = 128; o > 0; o >>= 1) {
    if (threadIdx.x < o) {
      float m1 = sm_m[threadIdx.x], s1 = sm_s[threadIdx.x];
      float m2 = sm_m[threadIdx.x + o], s2 = sm_s[threadIdx.x + o];
      float M = fmaxf(m1, m2);
      sm_s[threadIdx.x] = s1 * expf(m1 - M) + s2 * expf(m2 - M);
      sm_m[threadIdx.x] = M;
    }
    __syncthreads();
  }
  if (threadIdx.x == 0) { finals[0] = sm_m[0]; finals[1] = sm_s[0]; }
}

__global__ void k_sm_out(const float* __restrict__ s, int n,
                         const float* __restrict__ finals, float* __restrict__ out) {
  int i = blockIdx.x * 256 + threadIdx.x;
  if (i < n) out[i] = expf(s[i] - finals[0]) / finals[1];
}

extern "C" void kernel_launch(void* const* d_in, const int* in_sizes, int n_in,
                              void* d_out, int out_size, void* d_ws, size_t ws_size,
                              hipStream_t stream) {
  const float* x    = (const float*)d_in[0];
  const int*   ei   = (const int*)d_in[1];
  const float* W1   = (const float*)d_in[2];
  const float* b1   = (const float*)d_in[3];
  const float* W2   = (const float*)d_in[4];
  const float* b2   = (const float*)d_in[5];
  const float* Wh   = (const float*)d_in[6];
  const float* bh   = (const float*)d_in[7];
  const float* cash = (const float*)d_in[8];

  const int N = in_sizes[0] / 128;
  const int E = in_sizes[1] / 2;
  const int* src = ei;
  const int* dst = ei + E;
  const int nbuk = cdiv(N, 512);  // 196 for N=100000 (<= NBMAX)
  const int nsb  = cdiv((long)N * 4, 256);  // gather_score blocks (= partials)

  char* p = (char*)d_ws;
  float* dinv   = (float*)p; p += sizeof(float) * N;
  u16*   hWs1   = (u16*)p;   p += sizeof(u16) * (size_t)N * 32;
  u16*   hWs2   = (u16*)p;   p += sizeof(u16) * (size_t)N * 32;
  float* scores = (float*)p; p += sizeof(float) * (N + 1);
  float2* part  = (float2*)p; p += sizeof(float2) * (size_t)nsb;
  float* finals = (float*)p; p += sizeof(float) * 4;
  unsigned* gcur  = (unsigned*)p; p += sizeof(unsigned) * NBMAX;
  unsigned* bbase = (unsigned*)p; p += sizeof(unsigned) * NBMAX;
  int* rowptr = (int*)p; p += sizeof(int) * (N + 1);
  unsigned* ebuf = (unsigned*)p; p += sizeof(unsigned) * (size_t)nbuk * CAP;
  int* esrc   = (int*)p; p += sizeof(int) * (size_t)E;
  float* out = (float*)d_out;
  const int n = N + 1;

  // --- CSR build (coarse-bucket counting sort; shared by both layers) ---
  k_zero<<<1, 256, 0, stream>>>(gcur, NBMAX);
  k_bin<<<cdiv(E, EPB), 512, 0, stream>>>(src, dst, gcur, ebuf, E, nbuk);
  k_bukscan<<<1, 256, 0, stream>>>(gcur, bbase, rowptr, nbuk, N);
  k_place<<<nbuk, 1024, 0, stream>>>(gcur, ebuf, bbase, rowptr, dinv, esrc, N);

  // --- layer 1 (+ fused layer-2 transform) ---
  k_gemm1<<<cdiv((long)N * 2, 256), 256, 0, stream>>>(x, W1, dinv, hWs1, N);
  k_gather_fuse<<<cdiv((long)N * 8, 256), 256, 0, stream>>>(
      esrc, rowptr, dinv, (const uint2*)hWs1, b1, W2, (uint2*)hWs2, N);

  // --- layer 2 gather + score head + softmax partials ---
  k_gather_score<<<nsb, 256, 0, stream>>>(
      esrc, rowptr, dinv, (const uint4*)hWs2, b2, Wh, bh, cash, scores, part, N);

  // --- softmax finish (2 kernels) ---
  k_sm_fin<<<1, 256, 0, stream>>>(part, nsb, scores, finals);
  k_sm_out<<<cdiv(n, 256), 256, 0, stream>>>(scores, n, finals, out);
}

// Round 19
// 196.550 us; speedup vs baseline: 1.1124x; 1.1124x over previous
//
#include <hip/hip_runtime.h>
#include <math.h>

// GCN forward: coarse-bucket counting-sort CSR + node-parallel bf16 gather.
// Measured models (R4-R18):
//   - device-scope atomic ~= 35B fabric + ~41ns -> minimize atomic COUNT.
//   - k_bin WRITE scales with fragments = blocks x buckets; bin at floor
//     ~40us (R17 512thr null). Do not touch.
//   - gathers instruction-bound: 8 lanes/node uint2 (R15). Broadcast esrc
//     loads (R13: shfl-distribution serializes row loads).
//   - gemm1: R18 split-K FAILED (6.4M LDS bank conflicts: pair lanes read w
//     8192B apart = same bank; +shfl combine, VGPR 40). THIS ROUND:
//     OUTPUT-split (lane h = cols [16h,16h+16), all k): pair reads same x
//     addr (merged), w reads 64B apart (different banks), no combine,
//     acc=16 VGPR, bitwise-identical results. 2x waves.
// Pipeline: k_zero -> k_bin(512thr) -> k_bukscan -> k_place(1024thr) ->
//   k_gemm1(output-split) -> k_gather_fuse(8-lane) ->
//   k_gather_score(8-lane, +softmax partial) -> k_sm_fin -> k_sm_out.

static inline int cdiv(long a, int b) { return (int)((a + (long)b - 1) / b); }

#define EPB 8192      // edges per k_bin block (391 blocks @ E=3.2M)
#define NBMAX 256     // max buckets (N <= 131072 @ 512 nodes/bucket)
#define CAP 17408     // per-bucket capacity; mean 16384, +8 sigma

typedef unsigned short u16;
typedef int iv4 __attribute__((ext_vector_type(4)));

__device__ __forceinline__ u16 f2bf(float f) {  // RNE f32->bf16
  unsigned u = __float_as_uint(f);
  return (u16)((u + 0x7FFFu + ((u >> 16) & 1u)) >> 16);
}
__device__ __forceinline__ float lo16f(unsigned v) {
  return __uint_as_float(v << 16);
}
__device__ __forceinline__ float hi16f(unsigned v) {
  return __uint_as_float(v & 0xFFFF0000u);
}

__global__ void k_zero(unsigned* __restrict__ p, int n) {
  int i = threadIdx.x;
  if (i < n) p[i] = 0u;
}

// --- binning: LDS hist -> one reservation atomic per (block,bucket) -> fill runs
__global__ __launch_bounds__(512) void k_bin(const int* __restrict__ src,
                                             const int* __restrict__ dst,
                                             unsigned* __restrict__ gcur,
                                             unsigned* __restrict__ ebuf,
                                             int E, int nbuk) {
  __shared__ unsigned lhist[NBMAX];
  __shared__ unsigned lcur[NBMAX];
  int tid = threadIdx.x;
  for (int i = tid; i < nbuk; i += 512) lhist[i] = 0;
  __syncthreads();
  int e0 = blockIdx.x * EPB, e1 = min(e0 + EPB, E);
  int nvec = (e1 - e0) >> 11;  // 2048-edge chunks (512 thr x 4)
  for (int k = 0; k < nvec; ++k) {
    iv4 d4 = __builtin_nontemporal_load((const iv4*)(dst + e0 + (k << 11) + tid * 4));
    atomicAdd(&lhist[d4.x >> 9], 1u);
    atomicAdd(&lhist[d4.y >> 9], 1u);
    atomicAdd(&lhist[d4.z >> 9], 1u);
    atomicAdd(&lhist[d4.w >> 9], 1u);
  }
  for (int e = e0 + (nvec << 11) + tid; e < e1; e += 512)
    atomicAdd(&lhist[__builtin_nontemporal_load(&dst[e]) >> 9], 1u);
  __syncthreads();
  for (int b = tid; b < nbuk; b += 512) {
    unsigned nn = lhist[b];
    lcur[b] = nn ? atomicAdd(&gcur[b], nn) : 0u;  // run reservation
  }
  __syncthreads();
  for (int k = 0; k < nvec; ++k) {
    int base = e0 + (k << 11) + tid * 4;
    iv4 d4 = __builtin_nontemporal_load((const iv4*)(dst + base));
    iv4 s4 = __builtin_nontemporal_load((const iv4*)(src + base));
#define PUT(dd, ss)                                              \
    {                                                            \
      int bb = (dd) >> 9;                                        \
      unsigned off = atomicAdd(&lcur[bb], 1u);                   \
      if (off < CAP)                                             \
        ebuf[(size_t)bb * CAP + off] =                           \
            ((unsigned)((dd) & 511) << 17) | (unsigned)(ss);     \
    }
    PUT(d4.x, s4.x) PUT(d4.y, s4.y) PUT(d4.z, s4.z) PUT(d4.w, s4.w)
  }
  for (int e = e0 + (nvec << 11) + tid; e < e1; e += 512) {
    int d = __builtin_nontemporal_load(&dst[e]);
    int s = __builtin_nontemporal_load(&src[e]);
    PUT(d, s)
  }
#undef PUT
}

// --- exclusive scan of bucket counts (one block; nbuk <= 256)
__global__ __launch_bounds__(256) void k_bukscan(const unsigned* __restrict__ gcur,
                                                 unsigned* __restrict__ bbase,
                                                 int* __restrict__ rowptr,
                                                 int nbuk, int N) {
  __shared__ unsigned sm[256];
  int t = threadIdx.x;
  unsigned v = (t < nbuk) ? min(gcur[t], (unsigned)CAP) : 0u;
  sm[t] = v;
  __syncthreads();
  for (int o = 1; o < 256; o <<= 1) {
    unsigned add = (t >= o) ? sm[t - o] : 0u;
    __syncthreads();
    sm[t] += add;
    __syncthreads();
  }
  if (t < nbuk) bbase[t] = sm[t] - v;  // exclusive
  if (t == 255) rowptr[N] = (int)sm[255];
}

// --- per-bucket (512 nodes, 1024 threads): LDS count+scan -> rowptr/dinv;
// sort run into esrc.
__global__ __launch_bounds__(1024) void k_place(const unsigned* __restrict__ gcur,
                                                const unsigned* __restrict__ ebuf,
                                                const unsigned* __restrict__ bbase,
                                                int* __restrict__ rowptr,
                                                float* __restrict__ dinv,
                                                int* __restrict__ esrc, int N) {
  __shared__ unsigned lcnt[512];
  __shared__ unsigned lofs[512];
  int b = blockIdx.x, tid = threadIdx.x;
  if (tid < 512) lcnt[tid] = 0;
  __syncthreads();
  int cnt = min((int)gcur[b], CAP);
  const unsigned* eb = ebuf + (size_t)b * CAP;
  for (int j = tid; j < cnt; j += 1024) atomicAdd(&lcnt[eb[j] >> 17], 1u);
  __syncthreads();
  unsigned myc = (tid < 512) ? lcnt[tid] : 0u;
  if (tid < 512) lofs[tid] = myc;
  __syncthreads();
  for (int o = 1; o < 512; o <<= 1) {  // inclusive scan over 512
    unsigned add = (tid < 512 && tid >= o) ? lofs[tid - o] : 0u;
    __syncthreads();
    if (tid < 512) lofs[tid] += add;
    __syncthreads();
  }
  unsigned base = bbase[b];
  if (tid < 512) {
    unsigned ex = lofs[tid] - myc;  // exclusive
    int node = (b << 9) + tid;
    if (node < N) {
      rowptr[node] = (int)(base + ex);
      dinv[node] = rsqrtf((float)myc + 1.0f);  // deg = cnt + self-loop
    }
    lofs[tid] = ex;  // reuse as cursor
  }
  __syncthreads();
  for (int j = tid; j < cnt; j += 1024) {
    unsigned p = eb[j];
    unsigned r = atomicAdd(&lofs[p >> 17], 1u);  // LDS atomic
    esrc[base + r] = (int)(p & 0x1FFFF);
  }
}

// hWs = bf16(dinv[r] * (x @ W1)); OUTPUT-SPLIT: 2 lanes/row, lane h computes
// cols [16h,16h+16) over all k. Pair lanes load the SAME x address (merged);
// w reads 64B apart (no bank conflict); no combine; acc = 16 VGPR.
__global__ __launch_bounds__(256) void k_gemm1(
    const float* __restrict__ x, const float* __restrict__ W1,
    const float* __restrict__ dinv, u16* __restrict__ hWs, int N) {
  __shared__ float4 w[128 * 8];  // w[k][q] = W1[k][4q..4q+3]
  for (int i = threadIdx.x; i < 1024; i += 256) w[i] = ((const float4*)W1)[i];
  __syncthreads();
  int gid = blockIdx.x * 256 + threadIdx.x;
  int r = gid >> 1, h = gid & 1;
  if (r >= N) return;
  const float4* xr = (const float4*)(x + (size_t)r * 128);
  float acc[16];
#pragma unroll
  for (int c = 0; c < 16; ++c) acc[c] = 0.f;
  for (int k4 = 0; k4 < 32; ++k4) {
    float4 xv = xr[k4];  // same addr for lanes 2i,2i+1 -> merged request
#pragma unroll
    for (int kk = 0; kk < 4; ++kk) {
      float xk = (kk == 0) ? xv.x : (kk == 1) ? xv.y : (kk == 2) ? xv.z : xv.w;
      const float4* wk = &w[(k4 * 4 + kk) * 8 + h * 4];
#pragma unroll
      for (int q = 0; q < 4; ++q) {
        float4 wv = wk[q];
        acc[q * 4 + 0] = fmaf(xk, wv.x, acc[q * 4 + 0]);
        acc[q * 4 + 1] = fmaf(xk, wv.y, acc[q * 4 + 1]);
        acc[q * 4 + 2] = fmaf(xk, wv.z, acc[q * 4 + 2]);
        acc[q * 4 + 3] = fmaf(xk, wv.w, acc[q * 4 + 3]);
      }
    }
  }
  float dv = dinv[r];
  unsigned pk[8];
#pragma unroll
  for (int q = 0; q < 8; ++q) {
    pk[q] = (unsigned)f2bf(dv * acc[2 * q]) |
            ((unsigned)f2bf(dv * acc[2 * q + 1]) << 16);
  }
  uint4* o4 = (uint4*)(hWs + (size_t)r * 32) + h * 2;
  o4[0] = make_uint4(pk[0], pk[1], pk[2], pk[3]);
  o4[1] = make_uint4(pk[4], pk[5], pk[6], pk[7]);
}

// accumulate 4 bf16 columns from packed uint2
#define ACC4(A, U)                \
  {                               \
    A.x += lo16f((U).x);          \
    A.y += hi16f((U).x);          \
    A.z += lo16f((U).y);          \
    A.w += hi16f((U).y);          \
  }

// layer-1 gather fused with layer-2 transform. 8 lanes/node, lane = 4 columns.
__global__ __launch_bounds__(256) void k_gather_fuse(
    const int* __restrict__ esrc, const int* __restrict__ rowptr,
    const float* __restrict__ dinv, const uint2* __restrict__ hWs1,
    const float* __restrict__ b1, const float* __restrict__ W2,
    uint2* __restrict__ hWs2, int N) {
  __shared__ float4 w2[32 * 8];  // w2[k][q] = W2[k][4q..4q+3]
  w2[threadIdx.x] = ((const float4*)W2)[threadIdx.x];
  __syncthreads();
  int gid = blockIdx.x * 256 + threadIdx.x;
  int i = gid >> 3, c = gid & 7;
  if (i >= N) return;
  uint2 v = hWs1[(size_t)i * 8 + c];
  float4 acc = make_float4(lo16f(v.x), hi16f(v.x), lo16f(v.y), hi16f(v.y));
  int beg = rowptr[i], end = rowptr[i + 1];
  int j = beg;
  for (; j + 7 < end; j += 8) {
    int s0 = esrc[j + 0], s1 = esrc[j + 1], s2 = esrc[j + 2], s3 = esrc[j + 3];
    int s4 = esrc[j + 4], s5 = esrc[j + 5], s6 = esrc[j + 6], s7 = esrc[j + 7];
    uint2 u0 = hWs1[(size_t)s0 * 8 + c];
    uint2 u1 = hWs1[(size_t)s1 * 8 + c];
    uint2 u2 = hWs1[(size_t)s2 * 8 + c];
    uint2 u3 = hWs1[(size_t)s3 * 8 + c];
    uint2 u4 = hWs1[(size_t)s4 * 8 + c];
    uint2 u5 = hWs1[(size_t)s5 * 8 + c];
    uint2 u6 = hWs1[(size_t)s6 * 8 + c];
    uint2 u7 = hWs1[(size_t)s7 * 8 + c];
    ACC4(acc, u0) ACC4(acc, u1) ACC4(acc, u2) ACC4(acc, u3)
    ACC4(acc, u4) ACC4(acc, u5) ACC4(acc, u6) ACC4(acc, u7)
  }
  for (; j < end; ++j) {
    uint2 u = hWs1[(size_t)esrc[j] * 8 + c];
    ACC4(acc, u)
  }
  float dv = dinv[i];
  float4 bv = ((const float4*)b1)[c];
  float4 r4;
  r4.x = fmaxf(fmaf(dv, acc.x, bv.x), 0.f);
  r4.y = fmaxf(fmaf(dv, acc.y, bv.y), 0.f);
  r4.z = fmaxf(fmaf(dv, acc.z, bv.z), 0.f);
  r4.w = fmaxf(fmaf(dv, acc.w, bv.w), 0.f);
  float4 a2 = make_float4(0.f, 0.f, 0.f, 0.f);
#pragma unroll
  for (int k8 = 0; k8 < 8; ++k8) {
    float4 rr;
    rr.x = __shfl(r4.x, k8, 8);
    rr.y = __shfl(r4.y, k8, 8);
    rr.z = __shfl(r4.z, k8, 8);
    rr.w = __shfl(r4.w, k8, 8);
    float4 wv;
    wv = w2[(4 * k8 + 0) * 8 + c];
    a2.x = fmaf(rr.x, wv.x, a2.x); a2.y = fmaf(rr.x, wv.y, a2.y);
    a2.z = fmaf(rr.x, wv.z, a2.z); a2.w = fmaf(rr.x, wv.w, a2.w);
    wv = w2[(4 * k8 + 1) * 8 + c];
    a2.x = fmaf(rr.y, wv.x, a2.x); a2.y = fmaf(rr.y, wv.y, a2.y);
    a2.z = fmaf(rr.y, wv.z, a2.z); a2.w = fmaf(rr.y, wv.w, a2.w);
    wv = w2[(4 * k8 + 2) * 8 + c];
    a2.x = fmaf(rr.z, wv.x, a2.x); a2.y = fmaf(rr.z, wv.y, a2.y);
    a2.z = fmaf(rr.z, wv.z, a2.z); a2.w = fmaf(rr.z, wv.w, a2.w);
    wv = w2[(4 * k8 + 3) * 8 + c];
    a2.x = fmaf(rr.w, wv.x, a2.x); a2.y = fmaf(rr.w, wv.y, a2.y);
    a2.z = fmaf(rr.w, wv.z, a2.z); a2.w = fmaf(rr.w, wv.w, a2.w);
  }
  uint2 o;
  o.x = (unsigned)f2bf(dv * a2.x) | ((unsigned)f2bf(dv * a2.y) << 16);
  o.y = (unsigned)f2bf(dv * a2.z) | ((unsigned)f2bf(dv * a2.w) << 16);
  hWs2[(size_t)i * 8 + c] = o;
}

// layer-2 gather + score head + per-block softmax partial (max, sumexp).
// 8 lanes/node, lane = 4 columns (R17 champion form).
__global__ __launch_bounds__(256) void k_gather_score(
    const int* __restrict__ esrc, const int* __restrict__ rowptr,
    const float* __restrict__ dinv, const uint2* __restrict__ hWs,
    const float* __restrict__ bias, const float* __restrict__ Wh,
    const float* __restrict__ bh, const float* __restrict__ cash,
    float* __restrict__ scores, float2* __restrict__ part, int N) {
  __shared__ float sc[32];
  int gid = blockIdx.x * 256 + threadIdx.x;
  if (gid == 0) scores[0] = cash[0];
  if (threadIdx.x < 32) sc[threadIdx.x] = -3.4e38f;
  __syncthreads();
  int i = gid >> 3, c = gid & 7;
  if (i < N) {
    uint2 v = hWs[(size_t)i * 8 + c];
    float4 acc = make_float4(lo16f(v.x), hi16f(v.x), lo16f(v.y), hi16f(v.y));
    int beg = rowptr[i], end = rowptr[i + 1];
    int j = beg;
    for (; j + 7 < end; j += 8) {
      int s0 = esrc[j + 0], s1 = esrc[j + 1], s2 = esrc[j + 2], s3 = esrc[j + 3];
      int s4 = esrc[j + 4], s5 = esrc[j + 5], s6 = esrc[j + 6], s7 = esrc[j + 7];
      uint2 u0 = hWs[(size_t)s0 * 8 + c];
      uint2 u1 = hWs[(size_t)s1 * 8 + c];
      uint2 u2 = hWs[(size_t)s2 * 8 + c];
      uint2 u3 = hWs[(size_t)s3 * 8 + c];
      uint2 u4 = hWs[(size_t)s4 * 8 + c];
      uint2 u5 = hWs[(size_t)s5 * 8 + c];
      uint2 u6 = hWs[(size_t)s6 * 8 + c];
      uint2 u7 = hWs[(size_t)s7 * 8 + c];
      ACC4(acc, u0) ACC4(acc, u1) ACC4(acc, u2) ACC4(acc, u3)
      ACC4(acc, u4) ACC4(acc, u5) ACC4(acc, u6) ACC4(acc, u7)
    }
    for (; j < end; ++j) {
      uint2 u = hWs[(size_t)esrc[j] * 8 + c];
      ACC4(acc, u)
    }
    float dv = dinv[i];
    float4 bv = ((const float4*)bias)[c];
    float4 wh = ((const float4*)Wh)[c];
    float t = fmaxf(fmaf(dv, acc.x, bv.x), 0.f) * wh.x +
              fmaxf(fmaf(dv, acc.y, bv.y), 0.f) * wh.y +
              fmaxf(fmaf(dv, acc.z, bv.z), 0.f) * wh.z +
              fmaxf(fmaf(dv, acc.w, bv.w), 0.f) * wh.w;
#pragma unroll
    for (int m = 4; m >= 1; m >>= 1) t += __shfl_xor(t, m, 8);
    if (c == 0) {
      float s = t + bh[0];
      scores[1 + i] = s;
      sc[threadIdx.x >> 3] = s;
    }
  }
  __syncthreads();
  if (threadIdx.x < 32) {  // exact (max,sumexp) over this block's 32 scores
    float m = sc[threadIdx.x];
#pragma unroll
    for (int o = 16; o >= 1; o >>= 1) m = fmaxf(m, __shfl_xor(m, o, 32));
    float e = (sc[threadIdx.x] > -3.0e38f) ? expf(sc[threadIdx.x] - m) : 0.f;
#pragma unroll
    for (int o = 16; o >= 1; o >>= 1) e += __shfl_xor(e, o, 32);
    if (threadIdx.x == 0) part[blockIdx.x] = make_float2(m, e);
  }
}

// --- final softmax reduce: merge block partials + cash (thread 0) ---
__global__ __launch_bounds__(256) void k_sm_fin(const float2* __restrict__ part,
                                                int nparts,
                                                const float* __restrict__ scores,
                                                float* __restrict__ finals) {
  float m = (threadIdx.x == 0) ? scores[0] : -3.4e38f;  // cash
  float s = (threadIdx.x == 0) ? 1.f : 0.f;
  for (int i = threadIdx.x; i < nparts; i += 256) {
    float2 p = part[i];
    if (p.x > m) { s = s * expf(m - p.x) + p.y; m = p.x; }
    else s += p.y * expf(p.x - m);
  }
  __shared__ float sm_m[256], sm_s[256];
  sm_m[threadIdx.x] = m; sm_s[threadIdx.x] = s;
  __syncthreads();
  for (int o = 128; o > 0; o >>= 1) {
    if (threadIdx.x < o) {
      float m1 = sm_m[threadIdx.x], s1 = sm_s[threadIdx.x];
      float m2 = sm_m[threadIdx.x + o], s2 = sm_s[threadIdx.x + o];
      float M = fmaxf(m1, m2);
      sm_s[threadIdx.x] = s1 * expf(m1 - M) + s2 * expf(m2 - M);
      sm_m[threadIdx.x] = M;
    }
    __syncthreads();
  }
  if (threadIdx.x == 0) { finals[0] = sm_m[0]; finals[1] = sm_s[0]; }
}

__global__ void k_sm_out(const float* __restrict__ s, int n,
                         const float* __restrict__ finals, float* __restrict__ out) {
  int i = blockIdx.x * 256 + threadIdx.x;
  if (i < n) out[i] = expf(s[i] - finals[0]) / finals[1];
}

extern "C" void kernel_launch(void* const* d_in, const int* in_sizes, int n_in,
                              void* d_out, int out_size, void* d_ws, size_t ws_size,
                              hipStream_t stream) {
  const float* x    = (const float*)d_in[0];
  const int*   ei   = (const int*)d_in[1];
  const float* W1   = (const float*)d_in[2];
  const float* b1   = (const float*)d_in[3];
  const float* W2   = (const float*)d_in[4];
  const float* b2   = (const float*)d_in[5];
  const float* Wh   = (const float*)d_in[6];
  const float* bh   = (const float*)d_in[7];
  const float* cash = (const float*)d_in[8];

  const int N = in_sizes[0] / 128;
  const int E = in_sizes[1] / 2;
  const int* src = ei;
  const int* dst = ei + E;
  const int nbuk = cdiv(N, 512);  // 196 for N=100000 (<= NBMAX)
  const int nsb  = cdiv((long)N * 8, 256);  // gather_score blocks (= partials)

  char* p = (char*)d_ws;
  float* dinv   = (float*)p; p += sizeof(float) * N;
  u16*   hWs1   = (u16*)p;   p += sizeof(u16) * (size_t)N * 32;
  u16*   hWs2   = (u16*)p;   p += sizeof(u16) * (size_t)N * 32;
  float* scores = (float*)p; p += sizeof(float) * (N + 1);
  float2* part  = (float2*)p; p += sizeof(float2) * (size_t)nsb;
  float* finals = (float*)p; p += sizeof(float) * 4;
  unsigned* gcur  = (unsigned*)p; p += sizeof(unsigned) * NBMAX;
  unsigned* bbase = (unsigned*)p; p += sizeof(unsigned) * NBMAX;
  int* rowptr = (int*)p; p += sizeof(int) * (N + 1);
  unsigned* ebuf = (unsigned*)p; p += sizeof(unsigned) * (size_t)nbuk * CAP;
  int* esrc   = (int*)p; p += sizeof(int) * (size_t)E;
  float* out = (float*)d_out;
  const int n = N + 1;

  // --- CSR build (coarse-bucket counting sort; shared by both layers) ---
  k_zero<<<1, 256, 0, stream>>>(gcur, NBMAX);
  k_bin<<<cdiv(E, EPB), 512, 0, stream>>>(src, dst, gcur, ebuf, E, nbuk);
  k_bukscan<<<1, 256, 0, stream>>>(gcur, bbase, rowptr, nbuk, N);
  k_place<<<nbuk, 1024, 0, stream>>>(gcur, ebuf, bbase, rowptr, dinv, esrc, N);

  // --- layer 1 (+ fused layer-2 transform) ---
  k_gemm1<<<cdiv((long)N * 2, 256), 256, 0, stream>>>(x, W1, dinv, hWs1, N);
  k_gather_fuse<<<cdiv((long)N * 8, 256), 256, 0, stream>>>(
      esrc, rowptr, dinv, (const uint2*)hWs1, b1, W2, (uint2*)hWs2, N);

  // --- layer 2 gather + score head + softmax partials ---
  k_gather_score<<<nsb, 256, 0, stream>>>(
      esrc, rowptr, dinv, (const uint2*)hWs2, b2, Wh, bh, cash, scores, part, N);

  // --- softmax finish (2 kernels) ---
  k_sm_fin<<<1, 256, 0, stream>>>(part, nsb, scores, finals);
  k_sm_out<<<cdiv(n, 256), 256, 0, stream>>>(scores, n, finals, out);
}

// Round 20
// 191.251 us; speedup vs baseline: 1.1432x; 1.0277x over previous
//
#include <hip/hip_runtime.h>
#include <math.h>

// GCN forward: coarse-bucket counting-sort CSR + node-parallel bf16 gather.
// Measured models (R4-R19):
//   - device-scope atomic ~= 35B fabric + ~41ns -> minimize atomic COUNT.
//   - k_bin WRITE scales with fragments = blocks x buckets; bin at floor
//     ~40us (R17 512thr null). Do not touch.
//   - gathers instruction-bound -> wide lanes (R15); broadcast esrc loads
//     (R13). R19: FETCH 110MB (random 64B lines, 6.4MB table vs 4MB XCD L2),
//     2.8 TB/s, occ 60%, VALU 30% -> mixed latency regime. THIS ROUND:
//     16-deep unroll (2x outstanding lines/wave).
//   - gemm1: output-split wins (R19); split-K loses (R18 bank conflicts).
//     THIS ROUND: 4-way output split (4x waves, acc=8 VGPR).
// Pipeline: k_zero -> k_bin(512thr) -> k_bukscan -> k_place(1024thr) ->
//   k_gemm1(4-way output-split) -> k_gather_fuse(8-lane,16-deep) ->
//   k_gather_score(8-lane,16-deep, +softmax partial) -> k_sm_fin -> k_sm_out.

static inline int cdiv(long a, int b) { return (int)((a + (long)b - 1) / b); }

#define EPB 8192      // edges per k_bin block (391 blocks @ E=3.2M)
#define NBMAX 256     // max buckets (N <= 131072 @ 512 nodes/bucket)
#define CAP 17408     // per-bucket capacity; mean 16384, +8 sigma

typedef unsigned short u16;
typedef int iv4 __attribute__((ext_vector_type(4)));

__device__ __forceinline__ u16 f2bf(float f) {  // RNE f32->bf16
  unsigned u = __float_as_uint(f);
  return (u16)((u + 0x7FFFu + ((u >> 16) & 1u)) >> 16);
}
__device__ __forceinline__ float lo16f(unsigned v) {
  return __uint_as_float(v << 16);
}
__device__ __forceinline__ float hi16f(unsigned v) {
  return __uint_as_float(v & 0xFFFF0000u);
}

__global__ void k_zero(unsigned* __restrict__ p, int n) {
  int i = threadIdx.x;
  if (i < n) p[i] = 0u;
}

// --- binning: LDS hist -> one reservation atomic per (block,bucket) -> fill runs
__global__ __launch_bounds__(512) void k_bin(const int* __restrict__ src,
                                             const int* __restrict__ dst,
                                             unsigned* __restrict__ gcur,
                                             unsigned* __restrict__ ebuf,
                                             int E, int nbuk) {
  __shared__ unsigned lhist[NBMAX];
  __shared__ unsigned lcur[NBMAX];
  int tid = threadIdx.x;
  for (int i = tid; i < nbuk; i += 512) lhist[i] = 0;
  __syncthreads();
  int e0 = blockIdx.x * EPB, e1 = min(e0 + EPB, E);
  int nvec = (e1 - e0) >> 11;  // 2048-edge chunks (512 thr x 4)
  for (int k = 0; k < nvec; ++k) {
    iv4 d4 = __builtin_nontemporal_load((const iv4*)(dst + e0 + (k << 11) + tid * 4));
    atomicAdd(&lhist[d4.x >> 9], 1u);
    atomicAdd(&lhist[d4.y >> 9], 1u);
    atomicAdd(&lhist[d4.z >> 9], 1u);
    atomicAdd(&lhist[d4.w >> 9], 1u);
  }
  for (int e = e0 + (nvec << 11) + tid; e < e1; e += 512)
    atomicAdd(&lhist[__builtin_nontemporal_load(&dst[e]) >> 9], 1u);
  __syncthreads();
  for (int b = tid; b < nbuk; b += 512) {
    unsigned nn = lhist[b];
    lcur[b] = nn ? atomicAdd(&gcur[b], nn) : 0u;  // run reservation
  }
  __syncthreads();
  for (int k = 0; k < nvec; ++k) {
    int base = e0 + (k << 11) + tid * 4;
    iv4 d4 = __builtin_nontemporal_load((const iv4*)(dst + base));
    iv4 s4 = __builtin_nontemporal_load((const iv4*)(src + base));
#define PUT(dd, ss)                                              \
    {                                                            \
      int bb = (dd) >> 9;                                        \
      unsigned off = atomicAdd(&lcur[bb], 1u);                   \
      if (off < CAP)                                             \
        ebuf[(size_t)bb * CAP + off] =                           \
            ((unsigned)((dd) & 511) << 17) | (unsigned)(ss);     \
    }
    PUT(d4.x, s4.x) PUT(d4.y, s4.y) PUT(d4.z, s4.z) PUT(d4.w, s4.w)
  }
  for (int e = e0 + (nvec << 11) + tid; e < e1; e += 512) {
    int d = __builtin_nontemporal_load(&dst[e]);
    int s = __builtin_nontemporal_load(&src[e]);
    PUT(d, s)
  }
#undef PUT
}

// --- exclusive scan of bucket counts (one block; nbuk <= 256)
__global__ __launch_bounds__(256) void k_bukscan(const unsigned* __restrict__ gcur,
                                                 unsigned* __restrict__ bbase,
                                                 int* __restrict__ rowptr,
                                                 int nbuk, int N) {
  __shared__ unsigned sm[256];
  int t = threadIdx.x;
  unsigned v = (t < nbuk) ? min(gcur[t], (unsigned)CAP) : 0u;
  sm[t] = v;
  __syncthreads();
  for (int o = 1; o < 256; o <<= 1) {
    unsigned add = (t >= o) ? sm[t - o] : 0u;
    __syncthreads();
    sm[t] += add;
    __syncthreads();
  }
  if (t < nbuk) bbase[t] = sm[t] - v;  // exclusive
  if (t == 255) rowptr[N] = (int)sm[255];
}

// --- per-bucket (512 nodes, 1024 threads): LDS count+scan -> rowptr/dinv;
// sort run into esrc.
__global__ __launch_bounds__(1024) void k_place(const unsigned* __restrict__ gcur,
                                                const unsigned* __restrict__ ebuf,
                                                const unsigned* __restrict__ bbase,
                                                int* __restrict__ rowptr,
                                                float* __restrict__ dinv,
                                                int* __restrict__ esrc, int N) {
  __shared__ unsigned lcnt[512];
  __shared__ unsigned lofs[512];
  int b = blockIdx.x, tid = threadIdx.x;
  if (tid < 512) lcnt[tid] = 0;
  __syncthreads();
  int cnt = min((int)gcur[b], CAP);
  const unsigned* eb = ebuf + (size_t)b * CAP;
  for (int j = tid; j < cnt; j += 1024) atomicAdd(&lcnt[eb[j] >> 17], 1u);
  __syncthreads();
  unsigned myc = (tid < 512) ? lcnt[tid] : 0u;
  if (tid < 512) lofs[tid] = myc;
  __syncthreads();
  for (int o = 1; o < 512; o <<= 1) {  // inclusive scan over 512
    unsigned add = (tid < 512 && tid >= o) ? lofs[tid - o] : 0u;
    __syncthreads();
    if (tid < 512) lofs[tid] += add;
    __syncthreads();
  }
  unsigned base = bbase[b];
  if (tid < 512) {
    unsigned ex = lofs[tid] - myc;  // exclusive
    int node = (b << 9) + tid;
    if (node < N) {
      rowptr[node] = (int)(base + ex);
      dinv[node] = rsqrtf((float)myc + 1.0f);  // deg = cnt + self-loop
    }
    lofs[tid] = ex;  // reuse as cursor
  }
  __syncthreads();
  for (int j = tid; j < cnt; j += 1024) {
    unsigned p = eb[j];
    unsigned r = atomicAdd(&lofs[p >> 17], 1u);  // LDS atomic
    esrc[base + r] = (int)(p & 0x1FFFF);
  }
}

// hWs = bf16(dinv[r] * (x @ W1)); 4-WAY OUTPUT SPLIT: lane h computes cols
// [8h,8h+8) over all k. Quad lanes load the SAME x address (merged); w reads
// consecutive float4 pairs (no bank conflict); acc = 8 VGPR; 4x waves.
__global__ __launch_bounds__(256) void k_gemm1(
    const float* __restrict__ x, const float* __restrict__ W1,
    const float* __restrict__ dinv, u16* __restrict__ hWs, int N) {
  __shared__ float4 w[128 * 8];  // w[k][q] = W1[k][4q..4q+3]
  for (int i = threadIdx.x; i < 1024; i += 256) w[i] = ((const float4*)W1)[i];
  __syncthreads();
  int gid = blockIdx.x * 256 + threadIdx.x;
  int r = gid >> 2, h = gid & 3;
  if (r >= N) return;
  const float4* xr = (const float4*)(x + (size_t)r * 128);
  float acc[8];
#pragma unroll
  for (int c = 0; c < 8; ++c) acc[c] = 0.f;
  for (int k4 = 0; k4 < 32; ++k4) {
    float4 xv = xr[k4];  // same addr for quad lanes -> merged request
#pragma unroll
    for (int kk = 0; kk < 4; ++kk) {
      float xk = (kk == 0) ? xv.x : (kk == 1) ? xv.y : (kk == 2) ? xv.z : xv.w;
      const float4* wk = &w[(k4 * 4 + kk) * 8 + h * 2];
#pragma unroll
      for (int q = 0; q < 2; ++q) {
        float4 wv = wk[q];
        acc[q * 4 + 0] = fmaf(xk, wv.x, acc[q * 4 + 0]);
        acc[q * 4 + 1] = fmaf(xk, wv.y, acc[q * 4 + 1]);
        acc[q * 4 + 2] = fmaf(xk, wv.z, acc[q * 4 + 2]);
        acc[q * 4 + 3] = fmaf(xk, wv.w, acc[q * 4 + 3]);
      }
    }
  }
  float dv = dinv[r];
  unsigned pk[4];
#pragma unroll
  for (int q = 0; q < 4; ++q) {
    pk[q] = (unsigned)f2bf(dv * acc[2 * q]) |
            ((unsigned)f2bf(dv * acc[2 * q + 1]) << 16);
  }
  ((uint4*)(hWs + (size_t)r * 32))[h] = make_uint4(pk[0], pk[1], pk[2], pk[3]);
}

// accumulate 4 bf16 columns from packed uint2
#define ACC4(A, U)                \
  {                               \
    A.x += lo16f((U).x);          \
    A.y += hi16f((U).x);          \
    A.z += lo16f((U).y);          \
    A.w += hi16f((U).y);          \
  }

// 16 broadcast esrc loads + 16 independent uint2 row loads in flight
#define GATHER_BODY(TBL)                                                  \
  for (; j + 15 < end; j += 16) {                                         \
    int t0 = esrc[j + 0], t1 = esrc[j + 1], t2 = esrc[j + 2],             \
        t3 = esrc[j + 3], t4 = esrc[j + 4], t5 = esrc[j + 5],             \
        t6 = esrc[j + 6], t7 = esrc[j + 7], t8 = esrc[j + 8],             \
        t9 = esrc[j + 9], tA = esrc[j + 10], tB = esrc[j + 11],           \
        tC = esrc[j + 12], tD = esrc[j + 13], tE = esrc[j + 14],          \
        tF = esrc[j + 15];                                                \
    uint2 q0 = TBL[(size_t)t0 * 8 + c], q1 = TBL[(size_t)t1 * 8 + c];     \
    uint2 q2 = TBL[(size_t)t2 * 8 + c], q3 = TBL[(size_t)t3 * 8 + c];     \
    uint2 q4 = TBL[(size_t)t4 * 8 + c], q5 = TBL[(size_t)t5 * 8 + c];     \
    uint2 q6 = TBL[(size_t)t6 * 8 + c], q7 = TBL[(size_t)t7 * 8 + c];     \
    uint2 q8 = TBL[(size_t)t8 * 8 + c], q9 = TBL[(size_t)t9 * 8 + c];     \
    uint2 qA = TBL[(size_t)tA * 8 + c], qB = TBL[(size_t)tB * 8 + c];     \
    uint2 qC = TBL[(size_t)tC * 8 + c], qD = TBL[(size_t)tD * 8 + c];     \
    uint2 qE = TBL[(size_t)tE * 8 + c], qF = TBL[(size_t)tF * 8 + c];     \
    ACC4(acc, q0) ACC4(acc, q1) ACC4(acc, q2) ACC4(acc, q3)               \
    ACC4(acc, q4) ACC4(acc, q5) ACC4(acc, q6) ACC4(acc, q7)               \
    ACC4(acc, q8) ACC4(acc, q9) ACC4(acc, qA) ACC4(acc, qB)               \
    ACC4(acc, qC) ACC4(acc, qD) ACC4(acc, qE) ACC4(acc, qF)               \
  }                                                                       \
  for (; j + 7 < end; j += 8) {                                           \
    int t0 = esrc[j + 0], t1 = esrc[j + 1], t2 = esrc[j + 2],             \
        t3 = esrc[j + 3], t4 = esrc[j + 4], t5 = esrc[j + 5],             \
        t6 = esrc[j + 6], t7 = esrc[j + 7];                               \
    uint2 q0 = TBL[(size_t)t0 * 8 + c], q1 = TBL[(size_t)t1 * 8 + c];     \
    uint2 q2 = TBL[(size_t)t2 * 8 + c], q3 = TBL[(size_t)t3 * 8 + c];     \
    uint2 q4 = TBL[(size_t)t4 * 8 + c], q5 = TBL[(size_t)t5 * 8 + c];     \
    uint2 q6 = TBL[(size_t)t6 * 8 + c], q7 = TBL[(size_t)t7 * 8 + c];     \
    ACC4(acc, q0) ACC4(acc, q1) ACC4(acc, q2) ACC4(acc, q3)               \
    ACC4(acc, q4) ACC4(acc, q5) ACC4(acc, q6) ACC4(acc, q7)               \
  }                                                                       \
  for (; j < end; ++j) {                                                  \
    uint2 u = TBL[(size_t)esrc[j] * 8 + c];                               \
    ACC4(acc, u)                                                          \
  }

// layer-1 gather fused with layer-2 transform. 8 lanes/node, lane = 4 columns.
__global__ __launch_bounds__(256) void k_gather_fuse(
    const int* __restrict__ esrc, const int* __restrict__ rowptr,
    const float* __restrict__ dinv, const uint2* __restrict__ hWs1,
    const float* __restrict__ b1, const float* __restrict__ W2,
    uint2* __restrict__ hWs2, int N) {
  __shared__ float4 w2[32 * 8];  // w2[k][q] = W2[k][4q..4q+3]
  w2[threadIdx.x] = ((const float4*)W2)[threadIdx.x];
  __syncthreads();
  int gid = blockIdx.x * 256 + threadIdx.x;
  int i = gid >> 3, c = gid & 7;
  if (i >= N) return;
  uint2 v = hWs1[(size_t)i * 8 + c];
  float4 acc = make_float4(lo16f(v.x), hi16f(v.x), lo16f(v.y), hi16f(v.y));
  int beg = rowptr[i], end = rowptr[i + 1];
  int j = beg;
  GATHER_BODY(hWs1)
  float dv = dinv[i];
  float4 bv = ((const float4*)b1)[c];
  float4 r4;
  r4.x = fmaxf(fmaf(dv, acc.x, bv.x), 0.f);
  r4.y = fmaxf(fmaf(dv, acc.y, bv.y), 0.f);
  r4.z = fmaxf(fmaf(dv, acc.z, bv.z), 0.f);
  r4.w = fmaxf(fmaf(dv, acc.w, bv.w), 0.f);
  float4 a2 = make_float4(0.f, 0.f, 0.f, 0.f);
#pragma unroll
  for (int k8 = 0; k8 < 8; ++k8) {
    float4 rr;
    rr.x = __shfl(r4.x, k8, 8);
    rr.y = __shfl(r4.y, k8, 8);
    rr.z = __shfl(r4.z, k8, 8);
    rr.w = __shfl(r4.w, k8, 8);
    float4 wv;
    wv = w2[(4 * k8 + 0) * 8 + c];
    a2.x = fmaf(rr.x, wv.x, a2.x); a2.y = fmaf(rr.x, wv.y, a2.y);
    a2.z = fmaf(rr.x, wv.z, a2.z); a2.w = fmaf(rr.x, wv.w, a2.w);
    wv = w2[(4 * k8 + 1) * 8 + c];
    a2.x = fmaf(rr.y, wv.x, a2.x); a2.y = fmaf(rr.y, wv.y, a2.y);
    a2.z = fmaf(rr.y, wv.z, a2.z); a2.w = fmaf(rr.y, wv.w, a2.w);
    wv = w2[(4 * k8 + 2) * 8 + c];
    a2.x = fmaf(rr.z, wv.x, a2.x); a2.y = fmaf(rr.z, wv.y, a2.y);
    a2.z = fmaf(rr.z, wv.z, a2.z); a2.w = fmaf(rr.z, wv.w, a2.w);
    wv = w2[(4 * k8 + 3) * 8 + c];
    a2.x = fmaf(rr.w, wv.x, a2.x); a2.y = fmaf(rr.w, wv.y, a2.y);
    a2.z = fmaf(rr.w, wv.z, a2.z); a2.w = fmaf(rr.w, wv.w, a2.w);
  }
  uint2 o;
  o.x = (unsigned)f2bf(dv * a2.x) | ((unsigned)f2bf(dv * a2.y) << 16);
  o.y = (unsigned)f2bf(dv * a2.z) | ((unsigned)f2bf(dv * a2.w) << 16);
  hWs2[(size_t)i * 8 + c] = o;
}

// layer-2 gather + score head + per-block softmax partial (max, sumexp).
__global__ __launch_bounds__(256) void k_gather_score(
    const int* __restrict__ esrc, const int* __restrict__ rowptr,
    const float* __restrict__ dinv, const uint2* __restrict__ hWs,
    const float* __restrict__ bias, const float* __restrict__ Wh,
    const float* __restrict__ bh, const float* __restrict__ cash,
    float* __restrict__ scores, float2* __restrict__ part, int N) {
  __shared__ float sc[32];
  int gid = blockIdx.x * 256 + threadIdx.x;
  if (gid == 0) scores[0] = cash[0];
  if (threadIdx.x < 32) sc[threadIdx.x] = -3.4e38f;
  __syncthreads();
  int i = gid >> 3, c = gid & 7;
  if (i < N) {
    uint2 v = hWs[(size_t)i * 8 + c];
    float4 acc = make_float4(lo16f(v.x), hi16f(v.x), lo16f(v.y), hi16f(v.y));
    int beg = rowptr[i], end = rowptr[i + 1];
    int j = beg;
    GATHER_BODY(hWs)
    float dv = dinv[i];
    float4 bv = ((const float4*)bias)[c];
    float4 wh = ((const float4*)Wh)[c];
    float t = fmaxf(fmaf(dv, acc.x, bv.x), 0.f) * wh.x +
              fmaxf(fmaf(dv, acc.y, bv.y), 0.f) * wh.y +
              fmaxf(fmaf(dv, acc.z, bv.z), 0.f) * wh.z +
              fmaxf(fmaf(dv, acc.w, bv.w), 0.f) * wh.w;
#pragma unroll
    for (int m = 4; m >= 1; m >>= 1) t += __shfl_xor(t, m, 8);
    if (c == 0) {
      float s = t + bh[0];
      scores[1 + i] = s;
      sc[threadIdx.x >> 3] = s;
    }
  }
  __syncthreads();
  if (threadIdx.x < 32) {  // exact (max,sumexp) over this block's 32 scores
    float m = sc[threadIdx.x];
#pragma unroll
    for (int o = 16; o >= 1; o >>= 1) m = fmaxf(m, __shfl_xor(m, o, 32));
    float e = (sc[threadIdx.x] > -3.0e38f) ? expf(sc[threadIdx.x] - m) : 0.f;
#pragma unroll
    for (int o = 16; o >= 1; o >>= 1) e += __shfl_xor(e, o, 32);
    if (threadIdx.x == 0) part[blockIdx.x] = make_float2(m, e);
  }
}

// --- final softmax reduce: merge block partials + cash (thread 0) ---
__global__ __launch_bounds__(256) void k_sm_fin(const float2* __restrict__ part,
                                                int nparts,
                                                const float* __restrict__ scores,
                                                float* __restrict__ finals) {
  float m = (threadIdx.x == 0) ? scores[0] : -3.4e38f;  // cash
  float s = (threadIdx.x == 0) ? 1.f : 0.f;
  for (int i = threadIdx.x; i < nparts; i += 256) {
    float2 p = part[i];
    if (p.x > m) { s = s * expf(m - p.x) + p.y; m = p.x; }
    else s += p.y * expf(p.x - m);
  }
  __shared__ float sm_m[256], sm_s[256];
  sm_m[threadIdx.x] = m; sm_s[threadIdx.x] = s;
  __syncthreads();
  for (int o = 128; o > 0; o >>= 1) {
    if (threadIdx.x < o) {
      float m1 = sm_m[threadIdx.x], s1 = sm_s[threadIdx.x];
      float m2 = sm_m[threadIdx.x + o], s2 = sm_s[threadIdx.x + o];
      float M = fmaxf(m1, m2);
      sm_s[threadIdx.x] = s1 * expf(m1 - M) + s2 * expf(m2 - M);
      sm_m[threadIdx.x] = M;
    }
    __syncthreads();
  }
  if (threadIdx.x == 0) { finals[0] = sm_m[0]; finals[1] = sm_s[0]; }
}

__global__ void k_sm_out(const float* __restrict__ s, int n,
                         const float* __restrict__ finals, float* __restrict__ out) {
  int i = blockIdx.x * 256 + threadIdx.x;
  if (i < n) out[i] = expf(s[i] - finals[0]) / finals[1];
}

extern "C" void kernel_launch(void* const* d_in, const int* in_sizes, int n_in,
                              void* d_out, int out_size, void* d_ws, size_t ws_size,
                              hipStream_t stream) {
  const float* x    = (const float*)d_in[0];
  const int*   ei   = (const int*)d_in[1];
  const float* W1   = (const float*)d_in[2];
  const float* b1   = (const float*)d_in[3];
  const float* W2   = (const float*)d_in[4];
  const float* b2   = (const float*)d_in[5];
  const float* Wh   = (const float*)d_in[6];
  const float* bh   = (const float*)d_in[7];
  const float* cash = (const float*)d_in[8];

  const int N = in_sizes[0] / 128;
  const int E = in_sizes[1] / 2;
  const int* src = ei;
  const int* dst = ei + E;
  const int nbuk = cdiv(N, 512);  // 196 for N=100000 (<= NBMAX)
  const int nsb  = cdiv((long)N * 8, 256);  // gather_score blocks (= partials)

  char* p = (char*)d_ws;
  float* dinv   = (float*)p; p += sizeof(float) * N;
  u16*   hWs1   = (u16*)p;   p += sizeof(u16) * (size_t)N * 32;
  u16*   hWs2   = (u16*)p;   p += sizeof(u16) * (size_t)N * 32;
  float* scores = (float*)p; p += sizeof(float) * (N + 1);
  float2* part  = (float2*)p; p += sizeof(float2) * (size_t)nsb;
  float* finals = (float*)p; p += sizeof(float) * 4;
  unsigned* gcur  = (unsigned*)p; p += sizeof(unsigned) * NBMAX;
  unsigned* bbase = (unsigned*)p; p += sizeof(unsigned) * NBMAX;
  int* rowptr = (int*)p; p += sizeof(int) * (N + 1);
  unsigned* ebuf = (unsigned*)p; p += sizeof(unsigned) * (size_t)nbuk * CAP;
  int* esrc   = (int*)p; p += sizeof(int) * (size_t)E;
  float* out = (float*)d_out;
  const int n = N + 1;

  // --- CSR build (coarse-bucket counting sort; shared by both layers) ---
  k_zero<<<1, 256, 0, stream>>>(gcur, NBMAX);
  k_bin<<<cdiv(E, EPB), 512, 0, stream>>>(src, dst, gcur, ebuf, E, nbuk);
  k_bukscan<<<1, 256, 0, stream>>>(gcur, bbase, rowptr, nbuk, N);
  k_place<<<nbuk, 1024, 0, stream>>>(gcur, ebuf, bbase, rowptr, dinv, esrc, N);

  // --- layer 1 (+ fused layer-2 transform) ---
  k_gemm1<<<cdiv((long)N * 4, 256), 256, 0, stream>>>(x, W1, dinv, hWs1, N);
  k_gather_fuse<<<cdiv((long)N * 8, 256), 256, 0, stream>>>(
      esrc, rowptr, dinv, (const uint2*)hWs1, b1, W2, (uint2*)hWs2, N);

  // --- layer 2 gather + score head + softmax partials ---
  k_gather_score<<<nsb, 256, 0, stream>>>(
      esrc, rowptr, dinv, (const uint2*)hWs2, b2, Wh, bh, cash, scores, part, N);

  // --- softmax finish (2 kernels) ---
  k_sm_fin<<<1, 256, 0, stream>>>(part, nsb, scores, finals);
  k_sm_out<<<cdiv(n, 256), 256, 0, stream>>>(scores, n, finals, out);
}